// Round 4
// baseline (435.703 us; speedup 1.0000x reference)
//
#include <hip/hip_runtime.h>
#include <stdint.h>

typedef unsigned short u16;
typedef __attribute__((ext_vector_type(8))) short short8;
typedef __attribute__((ext_vector_type(4))) float f32x4;

#define SEQ 2048
#define DM 1024
#define NB 4
#define ROWS (NB*SEQ)   // 8192

__device__ __forceinline__ u16 f2bf(float f) {
  union { float f; uint32_t u; } x; x.f = f;
  uint32_t u = x.u;
  uint32_t r = u + 0x7FFFu + ((u >> 16) & 1u);
  return (u16)(r >> 16);
}
__device__ __forceinline__ float bf2f(u16 h) {
  union { uint32_t u; float f; } x; x.u = ((uint32_t)h) << 16;
  return x.f;
}

__device__ __forceinline__ void g2l16(void* lds, const void* g) {
  __builtin_amdgcn_global_load_lds(
      (const __attribute__((address_space(1))) void*)g,
      (__attribute__((address_space(3))) void*)lds, 16, 0, 0);
}

// ---------------- convert: f32 -> bf16 (MODE 1 applies exp first) ----------
template<int MODE>
__global__ void k_cvt(const float* __restrict__ in, u16* __restrict__ out, int n4) {
  int i = blockIdx.x * 256 + threadIdx.x;
  if (i >= n4) return;
  float4 v = reinterpret_cast<const float4*>(in)[i];
  if (MODE == 1) { v.x = __expf(v.x); v.y = __expf(v.y); v.z = __expf(v.z); v.w = __expf(v.w); }
  ushort4 o;
  o.x = f2bf(v.x); o.y = f2bf(v.y); o.z = f2bf(v.z); o.w = f2bf(v.w);
  reinterpret_cast<ushort4*>(out)[i] = o;
}

// ---------------- GEMM: C[m,n] = sum_k A[m,k]*B[n,k]  (A:[M,K] B:[N,K] row-major bf16)
// MODE 0: bf16 out (+bias); MODE 1: bf16 sigmoid(acc+bias); MODE 2: f32 out (+bias if non-null)
template<int MODE>
__global__ __launch_bounds__(256)
void k_gemm(const u16* __restrict__ A, const u16* __restrict__ B,
            void* __restrict__ C, const float* __restrict__ bias,
            int K, int lda, int ldb, int ldc,
            long sA, long sB, long sC)
{
  A += (long)blockIdx.z * sA;
  B += (long)blockIdx.z * sB;
  const int brow = blockIdx.y * 128;
  const int bcol = blockIdx.x * 128;
  __shared__ u16 As[128*32];
  __shared__ u16 Bs[128*32];
  const int tid = threadIdx.x;
  const int l  = tid & 63;
  const int w  = tid >> 6;
  const int wr = (w >> 1) * 64;
  const int wc = (w & 1) * 64;
  const int lr = l & 15;
  const int kg = l >> 4;

  f32x4 acc[4][4];
#pragma unroll
  for (int i = 0; i < 4; i++)
#pragma unroll
    for (int j = 0; j < 4; j++) acc[i][j] = (f32x4){0.f, 0.f, 0.f, 0.f};

  const int nkt = K >> 5;
  for (int kt = 0; kt < nkt; ++kt) {
    const u16* Ag = A + (long)brow * lda + kt * 32;
    const u16* Bg = B + (long)bcol * ldb + kt * 32;
#pragma unroll
    for (int i = 0; i < 2; ++i) {
      int c = i * 256 + tid;
      g2l16(&As[c * 8], Ag + (long)(c >> 2) * lda + (c & 3) * 8);
      g2l16(&Bs[c * 8], Bg + (long)(c >> 2) * ldb + (c & 3) * 8);
    }
    __syncthreads();
    short8 af[4], bf[4];
#pragma unroll
    for (int mi = 0; mi < 4; mi++) af[mi] = *(const short8*)&As[(wr + mi * 16 + lr) * 32 + kg * 8];
#pragma unroll
    for (int ni = 0; ni < 4; ni++) bf[ni] = *(const short8*)&Bs[(wc + ni * 16 + lr) * 32 + kg * 8];
#pragma unroll
    for (int mi = 0; mi < 4; mi++)
#pragma unroll
      for (int ni = 0; ni < 4; ni++)
        acc[mi][ni] = __builtin_amdgcn_mfma_f32_16x16x32_bf16(af[mi], bf[ni], acc[mi][ni], 0, 0, 0);
    __syncthreads();
  }

#pragma unroll
  for (int mi = 0; mi < 4; mi++) {
#pragma unroll
    for (int ni = 0; ni < 4; ni++) {
#pragma unroll
      for (int r = 0; r < 4; r++) {
        int row = brow + wr + mi * 16 + kg * 4 + r;
        int col = bcol + wc + ni * 16 + lr;
        float v = acc[mi][ni][r];
        if (bias) v += bias[col];
        if (MODE == 1) v = 1.f / (1.f + __expf(-v));
        long off = (long)blockIdx.z * sC + (long)row * ldc + col;
        if (MODE == 2) ((float*)C)[off] = v;
        else           ((u16*)C)[off] = f2bf(v);
      }
    }
  }
}

// ---------------- transpose + exp: Kb,Vb [b*T+s, e] bf16 -> Z[b][{eKV,eK}][e][s] bf16
__global__ void k_trans(const u16* __restrict__ Kb, const u16* __restrict__ Vb,
                        u16* __restrict__ Z) {
  __shared__ u16 lk[64][65];
  __shared__ u16 lv[64][65];
  int s0 = blockIdx.x * 64, e0 = blockIdx.y * 64, b = blockIdx.z;
  int tx = threadIdx.x & 63, ty = threadIdx.x >> 6;
  const long baseIn = (long)b * SEQ * DM;
  for (int j = ty; j < 64; j += 4) {
    lk[j][tx] = Kb[baseIn + (long)(s0 + j) * DM + e0 + tx];
    lv[j][tx] = Vb[baseIn + (long)(s0 + j) * DM + e0 + tx];
  }
  __syncthreads();
  const long ob = (long)b * 2 * DM * SEQ;
  for (int j = ty; j < 64; j += 4) {
    int e = e0 + j;
    float kf = bf2f(lk[tx][j]);
    float vf = bf2f(lv[tx][j]);
    float ek = __expf(kf);
    Z[ob + (long)e * SEQ + s0 + tx]        = f2bf(ek * vf);
    Z[ob + (long)(DM + e) * SEQ + s0 + tx] = f2bf(ek);
  }
}

// ---------------- combine: out1 = sigQ * numer/denom  -> bf16
__global__ void k_combine(const u16* __restrict__ Qs, const float* __restrict__ R,
                          u16* __restrict__ out1) {
  long i4 = (long)blockIdx.x * 256 + threadIdx.x;
  if (i4 >= (long)ROWS * DM / 4) return;
  long i = i4 * 4;
  int e = (int)(i & (DM - 1));
  long row = i >> 10;
  float4 nu = *(const float4*)&R[row * (2 * DM) + e];
  float4 de = *(const float4*)&R[row * (2 * DM) + DM + e];
  ushort4 q = *(const ushort4*)&Qs[i];
  ushort4 o;
  o.x = f2bf(bf2f(q.x) * nu.x / de.x);
  o.y = f2bf(bf2f(q.y) * nu.y / de.y);
  o.z = f2bf(bf2f(q.z) * nu.z / de.z);
  o.w = f2bf(bf2f(q.w) * nu.w / de.w);
  *(ushort4*)&out1[i] = o;
}

extern "C" void kernel_launch(void* const* d_in, const int* in_sizes, int n_in,
                              void* d_out, int out_size, void* d_ws, size_t ws_size,
                              hipStream_t stream)
{
  const float* x     = (const float*)d_in[0];
  const float* Wq    = (const float*)d_in[2];
  const float* bq    = (const float*)d_in[3];
  const float* Wk    = (const float*)d_in[4];
  const float* bk    = (const float*)d_in[5];
  const float* Wv    = (const float*)d_in[6];
  const float* bv    = (const float*)d_in[7];
  const float* Wo    = (const float*)d_in[8];
  const float* bo    = (const float*)d_in[9];
  const float* wbias = (const float*)d_in[10];

  char* ws = (char*)d_ws;
  u16*  xb  = (u16*)(ws);                      // 16.8 MB (reused as out1)
  u16*  Wqb = (u16*)(ws + 16777216);           // 4 x 2 MB
  u16*  Wkb = Wqb + 1024 * 1024;
  u16*  Wvb = Wkb + 1024 * 1024;
  u16*  Wob = Wvb + 1024 * 1024;
  u16*  EW  = (u16*)(ws + 25165824);           // 8.4 MB
  u16*  Qs  = (u16*)(ws + 33554432);           // 16.8 MB
  u16*  Kb  = (u16*)(ws + 50331648);           // 16.8 MB
  u16*  Vb  = (u16*)(ws + 67108864);           // 16.8 MB
  u16*  Z   = (u16*)(ws + 83886080);           // 33.6 MB
  float* R  = (float*)(ws + 117440512);        // 67.1 MB -> total 184.5 MB
  u16*  out1 = xb;

  // conversions
  k_cvt<0><<<ROWS * DM / 4 / 256, 256, 0, stream>>>(x, xb, ROWS * DM / 4);
  k_cvt<0><<<DM * DM / 4 / 256, 256, 0, stream>>>(Wq, Wqb, DM * DM / 4);
  k_cvt<0><<<DM * DM / 4 / 256, 256, 0, stream>>>(Wk, Wkb, DM * DM / 4);
  k_cvt<0><<<DM * DM / 4 / 256, 256, 0, stream>>>(Wv, Wvb, DM * DM / 4);
  k_cvt<0><<<DM * DM / 4 / 256, 256, 0, stream>>>(Wo, Wob, DM * DM / 4);
  k_cvt<1><<<SEQ * SEQ / 4 / 256, 256, 0, stream>>>(wbias, EW, SEQ * SEQ / 4);

  // Q/K/V projections (NT GEMMs)
  dim3 g1(DM / 128, ROWS / 128, 1);
  k_gemm<1><<<g1, 256, 0, stream>>>(xb, Wqb, Qs, bq, DM, DM, DM, DM, 0, 0, 0);
  k_gemm<0><<<g1, 256, 0, stream>>>(xb, Wkb, Kb, bk, DM, DM, DM, DM, 0, 0, 0);
  k_gemm<0><<<g1, 256, 0, stream>>>(xb, Wvb, Vb, bv, DM, DM, DM, DM, 0, 0, 0);

  // transpose + exp into Z
  dim3 gt(SEQ / 64, DM / 64, NB);
  k_trans<<<gt, 256, 0, stream>>>(Kb, Vb, Z);

  // AFT core: R[b] = EW @ Z[b]^T   (M=2048, N=2048, K=2048, batched over b)
  dim3 g2((2 * DM) / 128, SEQ / 128, NB);
  k_gemm<2><<<g2, 256, 0, stream>>>(EW, Z, R, nullptr, SEQ, SEQ, SEQ, 2 * DM,
                                    0, (long)2 * DM * SEQ, (long)SEQ * 2 * DM);

  // combine
  k_combine<<<ROWS * DM / 4 / 256, 256, 0, stream>>>(Qs, R, out1);

  // output projection -> f32 d_out
  k_gemm<2><<<g1, 256, 0, stream>>>(out1, Wob, (float*)d_out, bo, DM, DM, DM, DM, 0, 0, 0);
}

// Round 5
// 391.292 us; speedup vs baseline: 1.1135x; 1.1135x over previous
//
#include <hip/hip_runtime.h>
#include <stdint.h>

typedef unsigned short u16;
typedef __attribute__((ext_vector_type(8))) short short8;
typedef __attribute__((ext_vector_type(4))) float f32x4;

#define SEQ 2048
#define DM 1024
#define NB 4
#define ROWS (NB*SEQ)   // 8192

__device__ __forceinline__ u16 f2bf(float f) {
  union { float f; uint32_t u; } x; x.f = f;
  uint32_t u = x.u;
  uint32_t r = u + 0x7FFFu + ((u >> 16) & 1u);
  return (u16)(r >> 16);
}
__device__ __forceinline__ float bf2f(u16 h) {
  union { uint32_t u; float f; } x; x.u = ((uint32_t)h) << 16;
  return x.f;
}

__device__ __forceinline__ void g2l16(void* lds, const void* g) {
  __builtin_amdgcn_global_load_lds(
      (const __attribute__((address_space(1))) void*)g,
      (__attribute__((address_space(3))) void*)lds, 16, 0, 0);
}

// ---------------- convert: f32 -> bf16 (MODE 1 applies exp first) ----------
template<int MODE>
__global__ void k_cvt(const float* __restrict__ in, u16* __restrict__ out, int n4) {
  int i = blockIdx.x * 256 + threadIdx.x;
  if (i >= n4) return;
  float4 v = reinterpret_cast<const float4*>(in)[i];
  if (MODE == 1) { v.x = __expf(v.x); v.y = __expf(v.y); v.z = __expf(v.z); v.w = __expf(v.w); }
  ushort4 o;
  o.x = f2bf(v.x); o.y = f2bf(v.y); o.z = f2bf(v.z); o.w = f2bf(v.w);
  reinterpret_cast<ushort4*>(out)[i] = o;
}

// ---------------- 128^2 m97-structure GEMM (unchanged from baseline) -------
// C[m,n] = sum_k A[m,k]*B[n,k]  (A:[M,K] B:[N,K] row-major bf16)
// MODE 0: bf16 out (+bias); MODE 1: bf16 sigmoid(acc+bias); MODE 2: f32 out
template<int MODE>
__global__ __launch_bounds__(256)
void k_gemm(const u16* __restrict__ A, const u16* __restrict__ B,
            void* __restrict__ C, const float* __restrict__ bias,
            int K, int lda, int ldb, int ldc,
            long sA, long sB, long sC)
{
  A += (long)blockIdx.z * sA;
  B += (long)blockIdx.z * sB;
  const int brow = blockIdx.y * 128;
  const int bcol = blockIdx.x * 128;
  __shared__ u16 As[128*32];
  __shared__ u16 Bs[128*32];
  const int tid = threadIdx.x;
  const int l  = tid & 63;
  const int w  = tid >> 6;
  const int wr = (w >> 1) * 64;
  const int wc = (w & 1) * 64;
  const int lr = l & 15;
  const int kg = l >> 4;

  f32x4 acc[4][4];
#pragma unroll
  for (int i = 0; i < 4; i++)
#pragma unroll
    for (int j = 0; j < 4; j++) acc[i][j] = (f32x4){0.f, 0.f, 0.f, 0.f};

  const int nkt = K >> 5;
  for (int kt = 0; kt < nkt; ++kt) {
    const u16* Ag = A + (long)brow * lda + kt * 32;
    const u16* Bg = B + (long)bcol * ldb + kt * 32;
#pragma unroll
    for (int i = 0; i < 2; ++i) {
      int c = i * 256 + tid;
      g2l16(&As[c * 8], Ag + (long)(c >> 2) * lda + (c & 3) * 8);
      g2l16(&Bs[c * 8], Bg + (long)(c >> 2) * ldb + (c & 3) * 8);
    }
    __syncthreads();
    short8 af[4], bf[4];
#pragma unroll
    for (int mi = 0; mi < 4; mi++) af[mi] = *(const short8*)&As[(wr + mi * 16 + lr) * 32 + kg * 8];
#pragma unroll
    for (int ni = 0; ni < 4; ni++) bf[ni] = *(const short8*)&Bs[(wc + ni * 16 + lr) * 32 + kg * 8];
#pragma unroll
    for (int mi = 0; mi < 4; mi++)
#pragma unroll
      for (int ni = 0; ni < 4; ni++)
        acc[mi][ni] = __builtin_amdgcn_mfma_f32_16x16x32_bf16(af[mi], bf[ni], acc[mi][ni], 0, 0, 0);
    __syncthreads();
  }

#pragma unroll
  for (int mi = 0; mi < 4; mi++) {
#pragma unroll
    for (int ni = 0; ni < 4; ni++) {
#pragma unroll
      for (int r = 0; r < 4; r++) {
        int row = brow + wr + mi * 16 + kg * 4 + r;
        int col = bcol + wc + ni * 16 + lr;
        float v = acc[mi][ni][r];
        if (bias) v += bias[col];
        if (MODE == 1) v = 1.f / (1.f + __expf(-v));
        long off = (long)blockIdx.z * sC + (long)row * ldc + col;
        if (MODE == 2) ((float*)C)[off] = v;
        else           ((u16*)C)[off] = f2bf(v);
      }
    }
  }
}

// ---------------- AFT core: 256^2 / BK=64 / 8-wave, 8-phase-style schedule --
// C[b][m,n] = sum_k EW[m,k] * Z[b][n,k]   M=N=K=2048, f32 out.
// T2: (r&7)*16B XOR swizzle (same involution on pre-swizzled global source and
//     on ds_read addr; global_load_lds dest stays linear — rule #21).
// T3/T4: 2 LDS buffers, stage tile t+2 after tile t fully consumed; counted
//     vmcnt(8) per tile (= next tile's 8 in-flight wave-loads), vmcnt(0) only
//     at the last tile. T5: setprio around each 16-MFMA cluster.
#define STAGE(t_, bf_) do { \
  _Pragma("unroll") for (int h = 0; h < 2; ++h) { \
    _Pragma("unroll") for (int c = 0; c < 2; ++c) { \
      int idx = c * 512 + tid; \
      int r = idx >> 3; \
      int ce = ((idx & 7) ^ (r & 7)) * 8; \
      g2l16(&lds[(bf_)*32768 + h*8192 + idx*8], \
            Ag + (long)(h*128 + r)*2048 + (t_)*64 + ce); \
      g2l16(&lds[(bf_)*32768 + 16384 + h*8192 + idx*8], \
            Bg + (long)(h*128 + r)*2048 + (t_)*64 + ce); \
    } } } while (0)

#define LDA8(mh_) do { \
  _Pragma("unroll") for (int i = 0; i < 4; ++i) \
  _Pragma("unroll") for (int k = 0; k < 2; ++k) \
    a[i][k] = *(const short8*)&lds[ab + ((mh_)*64 + i*16 + lr)*64 + 8*(((k<<2)|kg) ^ (lr&7))]; \
  } while (0)

#define LDB8(nh_) do { \
  _Pragma("unroll") for (int j = 0; j < 2; ++j) \
  _Pragma("unroll") for (int k = 0; k < 2; ++k) \
    bn[nh_][j][k] = *(const short8*)&lds[bb + ((wn&1)*64 + ((nh_)*2+j)*16 + lr)*64 + 8*(((k<<2)|kg) ^ (lr&7))]; \
  } while (0)

#define MM8(mh_, nh_) do { \
  asm volatile("s_waitcnt lgkmcnt(0)" ::: "memory"); \
  __builtin_amdgcn_sched_barrier(0); \
  __builtin_amdgcn_s_setprio(1); \
  _Pragma("unroll") for (int i = 0; i < 4; ++i) \
  _Pragma("unroll") for (int j = 0; j < 2; ++j) \
  _Pragma("unroll") for (int k = 0; k < 2; ++k) \
    acc[(mh_)*4+i][(nh_)*2+j] = __builtin_amdgcn_mfma_f32_16x16x32_bf16( \
        a[i][k], bn[nh_][j][k], acc[(mh_)*4+i][(nh_)*2+j], 0, 0, 0); \
  __builtin_amdgcn_s_setprio(0); \
  } while (0)

__global__ __launch_bounds__(512)
void k_aft8(const u16* __restrict__ EW, const u16* __restrict__ Z,
            float* __restrict__ C)
{
  __shared__ u16 lds[65536];              // 128 KiB: 2 buf x (A 32K + B 32K)
  const int tid = threadIdx.x;
  const int l  = tid & 63, wid = tid >> 6;
  const int wm = wid >> 2, wn = wid & 3;  // 2 x 4 wave grid
  const int lr = l & 15,  kg = l >> 4;
  const int brow = blockIdx.y * 256;
  const int bcol = blockIdx.x * 256;
  const u16* Ag = EW + (long)brow * 2048;
  const u16* Bg = Z + (long)blockIdx.z * (2L * DM * SEQ) + (long)bcol * 2048;

  f32x4 acc[8][4];
#pragma unroll
  for (int m = 0; m < 8; ++m)
#pragma unroll
    for (int n = 0; n < 4; ++n) acc[m][n] = (f32x4){0.f, 0.f, 0.f, 0.f};

  short8 a[4][2], bn[2][2][2];

  STAGE(0, 0);
  STAGE(1, 1);

  for (int t = 0; t < 32; ++t) {
    const int bf = t & 1;
    if (t == 31) asm volatile("s_waitcnt vmcnt(0)" ::: "memory");
    else         asm volatile("s_waitcnt vmcnt(8)" ::: "memory");
    __builtin_amdgcn_s_barrier();
    __builtin_amdgcn_sched_barrier(0);
    const int ab = bf*32768 + wm*8192;
    const int bb = bf*32768 + 16384 + (wn>>1)*8192;
    LDA8(0); LDB8(0); MM8(0, 0);
    LDB8(1);          MM8(0, 1);
    LDA8(1);          MM8(1, 1);
                      MM8(1, 0);
    __builtin_amdgcn_sched_barrier(0);
    __builtin_amdgcn_s_barrier();
    if (t + 2 < 32) STAGE(t + 2, bf);
  }

  float* Cz = C + (long)blockIdx.z * ((long)SEQ * 2 * DM);
#pragma unroll
  for (int m = 0; m < 8; ++m)
#pragma unroll
    for (int n = 0; n < 4; ++n)
#pragma unroll
      for (int r = 0; r < 4; ++r) {
        int row = brow + wm*128 + m*16 + kg*4 + r;
        int col = bcol + wn*64 + n*16 + lr;
        Cz[(long)row * 2048 + col] = acc[m][n][r];
      }
}

// ---------------- transpose + exp: Kb,Vb [b*T+s, e] bf16 -> Z[b][{eKV,eK}][e][s] bf16
__global__ void k_trans(const u16* __restrict__ Kb, const u16* __restrict__ Vb,
                        u16* __restrict__ Z) {
  __shared__ u16 lk[64][65];
  __shared__ u16 lv[64][65];
  int s0 = blockIdx.x * 64, e0 = blockIdx.y * 64, b = blockIdx.z;
  int tx = threadIdx.x & 63, ty = threadIdx.x >> 6;
  const long baseIn = (long)b * SEQ * DM;
  for (int j = ty; j < 64; j += 4) {
    lk[j][tx] = Kb[baseIn + (long)(s0 + j) * DM + e0 + tx];
    lv[j][tx] = Vb[baseIn + (long)(s0 + j) * DM + e0 + tx];
  }
  __syncthreads();
  const long ob = (long)b * 2 * DM * SEQ;
  for (int j = ty; j < 64; j += 4) {
    int e = e0 + j;
    float kf = bf2f(lk[tx][j]);
    float vf = bf2f(lv[tx][j]);
    float ek = __expf(kf);
    Z[ob + (long)e * SEQ + s0 + tx]        = f2bf(ek * vf);
    Z[ob + (long)(DM + e) * SEQ + s0 + tx] = f2bf(ek);
  }
}

// ---------------- combine: out1 = sigQ * numer/denom  -> bf16
__global__ void k_combine(const u16* __restrict__ Qs, const float* __restrict__ R,
                          u16* __restrict__ out1) {
  long i4 = (long)blockIdx.x * 256 + threadIdx.x;
  if (i4 >= (long)ROWS * DM / 4) return;
  long i = i4 * 4;
  int e = (int)(i & (DM - 1));
  long row = i >> 10;
  float4 nu = *(const float4*)&R[row * (2 * DM) + e];
  float4 de = *(const float4*)&R[row * (2 * DM) + DM + e];
  ushort4 q = *(const ushort4*)&Qs[i];
  ushort4 o;
  o.x = f2bf(bf2f(q.x) * nu.x / de.x);
  o.y = f2bf(bf2f(q.y) * nu.y / de.y);
  o.z = f2bf(bf2f(q.z) * nu.z / de.z);
  o.w = f2bf(bf2f(q.w) * nu.w / de.w);
  *(ushort4*)&out1[i] = o;
}

extern "C" void kernel_launch(void* const* d_in, const int* in_sizes, int n_in,
                              void* d_out, int out_size, void* d_ws, size_t ws_size,
                              hipStream_t stream)
{
  const float* x     = (const float*)d_in[0];
  const float* Wq    = (const float*)d_in[2];
  const float* bq    = (const float*)d_in[3];
  const float* Wk    = (const float*)d_in[4];
  const float* bk    = (const float*)d_in[5];
  const float* Wv    = (const float*)d_in[6];
  const float* bv    = (const float*)d_in[7];
  const float* Wo    = (const float*)d_in[8];
  const float* bo    = (const float*)d_in[9];
  const float* wbias = (const float*)d_in[10];

  char* ws = (char*)d_ws;
  u16*  xb  = (u16*)(ws);                      // 16.8 MB (reused as out1)
  u16*  Wqb = (u16*)(ws + 16777216);           // 4 x 2 MB
  u16*  Wkb = Wqb + 1024 * 1024;
  u16*  Wvb = Wkb + 1024 * 1024;
  u16*  Wob = Wvb + 1024 * 1024;
  u16*  EW  = (u16*)(ws + 25165824);           // 8.4 MB
  u16*  Qs  = (u16*)(ws + 33554432);           // 16.8 MB
  u16*  Kb  = (u16*)(ws + 50331648);           // 16.8 MB
  u16*  Vb  = (u16*)(ws + 67108864);           // 16.8 MB
  u16*  Z   = (u16*)(ws + 83886080);           // 33.6 MB
  float* R  = (float*)(ws + 117440512);        // 67.1 MB -> total 184.5 MB
  u16*  out1 = xb;

  // conversions
  k_cvt<0><<<ROWS * DM / 4 / 256, 256, 0, stream>>>(x, xb, ROWS * DM / 4);
  k_cvt<0><<<DM * DM / 4 / 256, 256, 0, stream>>>(Wq, Wqb, DM * DM / 4);
  k_cvt<0><<<DM * DM / 4 / 256, 256, 0, stream>>>(Wk, Wkb, DM * DM / 4);
  k_cvt<0><<<DM * DM / 4 / 256, 256, 0, stream>>>(Wv, Wvb, DM * DM / 4);
  k_cvt<0><<<DM * DM / 4 / 256, 256, 0, stream>>>(Wo, Wob, DM * DM / 4);
  k_cvt<1><<<SEQ * SEQ / 4 / 256, 256, 0, stream>>>(wbias, EW, SEQ * SEQ / 4);

  // Q/K/V projections (NT GEMMs, unchanged)
  dim3 g1(DM / 128, ROWS / 128, 1);
  k_gemm<1><<<g1, 256, 0, stream>>>(xb, Wqb, Qs, bq, DM, DM, DM, DM, 0, 0, 0);
  k_gemm<0><<<g1, 256, 0, stream>>>(xb, Wkb, Kb, bk, DM, DM, DM, DM, 0, 0, 0);
  k_gemm<0><<<g1, 256, 0, stream>>>(xb, Wvb, Vb, bv, DM, DM, DM, DM, 0, 0, 0);

  // transpose + exp into Z
  dim3 gt(SEQ / 64, DM / 64, NB);
  k_trans<<<gt, 256, 0, stream>>>(Kb, Vb, Z);

  // AFT core: R[b] = EW @ Z[b]^T  — NEW 256^2 8-phase-style kernel
  dim3 g8(8, 8, NB);
  k_aft8<<<g8, 512, 0, stream>>>(EW, Z, R);

  // combine
  k_combine<<<ROWS * DM / 4 / 256, 256, 0, stream>>>(Qs, R, out1);

  // output projection -> f32 d_out
  k_gemm<2><<<g1, 256, 0, stream>>>(out1, Wob, (float*)d_out, bo, DM, DM, DM, DM, 0, 0, 0);
}

// Round 7
// 336.656 us; speedup vs baseline: 1.2942x; 1.1623x over previous
//
#include <hip/hip_runtime.h>
#include <stdint.h>

typedef unsigned short u16;
typedef __attribute__((ext_vector_type(8))) short short8;
typedef __attribute__((ext_vector_type(4))) float f32x4;

#define SEQ 2048
#define DM 1024
#define NB 4
#define ROWS (NB*SEQ)   // 8192

__device__ __forceinline__ u16 f2bf(float f) {
  union { float f; uint32_t u; } x; x.f = f;
  uint32_t u = x.u;
  uint32_t r = u + 0x7FFFu + ((u >> 16) & 1u);
  return (u16)(r >> 16);
}
__device__ __forceinline__ float bf2f(u16 h) {
  union { uint32_t u; float f; } x; x.u = ((uint32_t)h) << 16;
  return x.f;
}

__device__ __forceinline__ void g2l16(void* lds, const void* g) {
  __builtin_amdgcn_global_load_lds(
      (const __attribute__((address_space(1))) void*)g,
      (__attribute__((address_space(3))) void*)lds, 16, 0, 0);
}

// ---------------- convert: f32 -> bf16 (MODE 1 applies exp first) ----------
template<int MODE>
__global__ void k_cvt(const float* __restrict__ in, u16* __restrict__ out, int n4) {
  int i = blockIdx.x * 256 + threadIdx.x;
  if (i >= n4) return;
  float4 v = reinterpret_cast<const float4*>(in)[i];
  if (MODE == 1) { v.x = __expf(v.x); v.y = __expf(v.y); v.z = __expf(v.z); v.w = __expf(v.w); }
  ushort4 o;
  o.x = f2bf(v.x); o.y = f2bf(v.y); o.z = f2bf(v.z); o.w = f2bf(v.w);
  reinterpret_cast<ushort4*>(out)[i] = o;
}

// ---------------- 256^2 / BK=64 / 8-wave GEMM, 8-phase-style schedule -------
// C[m,n] = sum_k A[m,k] * B[n,k]; A:[M,KD] B:[N,KD] row-major bf16.
// T2 swizzle both-sides, counted vmcnt(8), setprio clusters.
// RACE FIX (R6): sched_barrier(0) AFTER the bottom s_barrier — s_barrier is
// not a compiler fence, and STAGE's global_load_lds was hoisted above it,
// overwriting the LDS buffer other waves were still reading (replay-divergence
// in R5). STAGE must stay pinned below the barrier.
// MODE 0: f32 out, ldc=2048, batched via blockIdx.z (AFT core).
// MODE 1: fused QKV epilogue — N=3072 in 3 segments {Q:sigmoid, K, V}, bf16,
//         seg outputs contiguous at C + seg*8388608, bias b0/b1/b2.
// MODE 2: f32 out + bias b0, ldc=1024 (out-proj).
#define STAGE(t_, bf_) do { \
  _Pragma("unroll") for (int h = 0; h < 2; ++h) { \
    _Pragma("unroll") for (int c = 0; c < 2; ++c) { \
      int idx = c * 512 + tid; \
      int r = idx >> 3; \
      int ce = ((idx & 7) ^ (r & 7)) * 8; \
      g2l16(&lds[(bf_)*32768 + h*8192 + idx*8], \
            Ag + (long)(h*128 + r)*KD + (t_)*64 + ce); \
      g2l16(&lds[(bf_)*32768 + 16384 + h*8192 + idx*8], \
            Bg + (long)(h*128 + r)*KD + (t_)*64 + ce); \
    } } } while (0)

#define LDA8(mh_) do { \
  _Pragma("unroll") for (int i = 0; i < 4; ++i) \
  _Pragma("unroll") for (int k = 0; k < 2; ++k) \
    a[i][k] = *(const short8*)&lds[ab + ((mh_)*64 + i*16 + lr)*64 + 8*(((k<<2)|kg) ^ (lr&7))]; \
  } while (0)

#define LDB8(nh_) do { \
  _Pragma("unroll") for (int j = 0; j < 2; ++j) \
  _Pragma("unroll") for (int k = 0; k < 2; ++k) \
    bn[nh_][j][k] = *(const short8*)&lds[bb + ((wn&1)*64 + ((nh_)*2+j)*16 + lr)*64 + 8*(((k<<2)|kg) ^ (lr&7))]; \
  } while (0)

#define MM8(mh_, nh_) do { \
  asm volatile("s_waitcnt lgkmcnt(0)" ::: "memory"); \
  __builtin_amdgcn_sched_barrier(0); \
  __builtin_amdgcn_s_setprio(1); \
  _Pragma("unroll") for (int i = 0; i < 4; ++i) \
  _Pragma("unroll") for (int j = 0; j < 2; ++j) \
  _Pragma("unroll") for (int k = 0; k < 2; ++k) \
    acc[(mh_)*4+i][(nh_)*2+j] = __builtin_amdgcn_mfma_f32_16x16x32_bf16( \
        a[i][k], bn[nh_][j][k], acc[(mh_)*4+i][(nh_)*2+j], 0, 0, 0); \
  __builtin_amdgcn_s_setprio(0); \
  } while (0)

template<int KD, int MODE>
__global__ __launch_bounds__(512)
void k_big(const u16* __restrict__ A, const u16* __restrict__ B,
           void* __restrict__ Cv,
           const float* __restrict__ b0, const float* __restrict__ b1,
           const float* __restrict__ b2, long sB, long sC)
{
  constexpr int NT = KD / 64;
  __shared__ u16 lds[65536];              // 128 KiB: 2 buf x (A 32K + B 32K)
  const int tid = threadIdx.x;
  const int l  = tid & 63, wid = tid >> 6;
  const int wm = wid >> 2, wn = wid & 3;  // 2 x 4 wave grid
  const int lr = l & 15,  kg = l >> 4;
  const int brow = blockIdx.y * 256;
  const int bcol = blockIdx.x * 256;
  const u16* Ag = A + (long)brow * KD;
  const u16* Bg = B + (long)blockIdx.z * sB + (long)bcol * KD;

  f32x4 acc[8][4];
#pragma unroll
  for (int m = 0; m < 8; ++m)
#pragma unroll
    for (int n = 0; n < 4; ++n) acc[m][n] = (f32x4){0.f, 0.f, 0.f, 0.f};

  short8 a[4][2], bn[2][2][2];

  STAGE(0, 0);
  STAGE(1, 1);

  for (int t = 0; t < NT; ++t) {
    const int bf = t & 1;
    if (t == NT - 1) asm volatile("s_waitcnt vmcnt(0)" ::: "memory");
    else             asm volatile("s_waitcnt vmcnt(8)" ::: "memory");
    __builtin_amdgcn_s_barrier();
    __builtin_amdgcn_sched_barrier(0);
    const int ab = bf*32768 + wm*8192;
    const int bb = bf*32768 + 16384 + (wn>>1)*8192;
    LDA8(0); LDB8(0); MM8(0, 0);
    LDB8(1);          MM8(0, 1);
    LDA8(1);          MM8(1, 1);
                      MM8(1, 0);
    __builtin_amdgcn_sched_barrier(0);
    __builtin_amdgcn_s_barrier();
    __builtin_amdgcn_sched_barrier(0);   // RACE FIX: pin STAGE below barrier
    if (t + 2 < NT) STAGE(t + 2, bf);
  }

#pragma unroll
  for (int m = 0; m < 8; ++m)
#pragma unroll
    for (int n = 0; n < 4; ++n)
#pragma unroll
      for (int r = 0; r < 4; ++r) {
        int row = brow + wm*128 + m*16 + kg*4 + r;
        int col = bcol + wn*64 + n*16 + lr;
        float v = acc[m][n][r];
        if (MODE == 0) {
          ((float*)Cv)[(long)blockIdx.z * sC + (long)row * 2048 + col] = v;
        } else if (MODE == 1) {
          int seg = col >> 10, colr = col & 1023;
          const float* bp = (seg == 0) ? b0 : (seg == 1) ? b1 : b2;
          v += bp[colr];
          if (seg == 0) v = 1.f / (1.f + __expf(-v));
          ((u16*)Cv)[(long)seg * 8388608 + (long)row * 1024 + colr] = f2bf(v);
        } else {
          ((float*)Cv)[(long)row * 1024 + col] = v + b0[col];
        }
      }
}

// ---------------- transpose + exp: Kb,Vb [b*T+s, e] bf16 -> Z[b][{eKV,eK}][e][s] bf16
__global__ void k_trans(const u16* __restrict__ Kb, const u16* __restrict__ Vb,
                        u16* __restrict__ Z) {
  __shared__ u16 lk[64][65];
  __shared__ u16 lv[64][65];
  int s0 = blockIdx.x * 64, e0 = blockIdx.y * 64, b = blockIdx.z;
  int tx = threadIdx.x & 63, ty = threadIdx.x >> 6;
  const long baseIn = (long)b * SEQ * DM;
  for (int j = ty; j < 64; j += 4) {
    lk[j][tx] = Kb[baseIn + (long)(s0 + j) * DM + e0 + tx];
    lv[j][tx] = Vb[baseIn + (long)(s0 + j) * DM + e0 + tx];
  }
  __syncthreads();
  const long ob = (long)b * 2 * DM * SEQ;
  for (int j = ty; j < 64; j += 4) {
    int e = e0 + j;
    float kf = bf2f(lk[tx][j]);
    float vf = bf2f(lv[tx][j]);
    float ek = __expf(kf);
    Z[ob + (long)e * SEQ + s0 + tx]        = f2bf(ek * vf);
    Z[ob + (long)(DM + e) * SEQ + s0 + tx] = f2bf(ek);
  }
}

// ---------------- combine: out1 = sigQ * numer/denom  -> bf16
__global__ void k_combine(const u16* __restrict__ Qs, const float* __restrict__ R,
                          u16* __restrict__ out1) {
  long i4 = (long)blockIdx.x * 256 + threadIdx.x;
  if (i4 >= (long)ROWS * DM / 4) return;
  long i = i4 * 4;
  int e = (int)(i & (DM - 1));
  long row = i >> 10;
  float4 nu = *(const float4*)&R[row * (2 * DM) + e];
  float4 de = *(const float4*)&R[row * (2 * DM) + DM + e];
  ushort4 q = *(const ushort4*)&Qs[i];
  ushort4 o;
  o.x = f2bf(bf2f(q.x) * nu.x / de.x);
  o.y = f2bf(bf2f(q.y) * nu.y / de.y);
  o.z = f2bf(bf2f(q.z) * nu.z / de.z);
  o.w = f2bf(bf2f(q.w) * nu.w / de.w);
  *(ushort4*)&out1[i] = o;
}

extern "C" void kernel_launch(void* const* d_in, const int* in_sizes, int n_in,
                              void* d_out, int out_size, void* d_ws, size_t ws_size,
                              hipStream_t stream)
{
  const float* x     = (const float*)d_in[0];
  const float* Wq    = (const float*)d_in[2];
  const float* bq    = (const float*)d_in[3];
  const float* Wk    = (const float*)d_in[4];
  const float* bk    = (const float*)d_in[5];
  const float* Wv    = (const float*)d_in[6];
  const float* bv    = (const float*)d_in[7];
  const float* Wo    = (const float*)d_in[8];
  const float* bo    = (const float*)d_in[9];
  const float* wbias = (const float*)d_in[10];

  char* ws = (char*)d_ws;
  u16*  xb  = (u16*)(ws);                      // 16.8 MB (reused as out1)
  u16*  Wqb = (u16*)(ws + 16777216);           // Wq/Wk/Wv contiguous = Wall[3072][1024]
  u16*  Wkb = Wqb + 1024 * 1024;
  u16*  Wvb = Wkb + 1024 * 1024;
  u16*  Wob = Wvb + 1024 * 1024;
  u16*  EW  = (u16*)(ws + 25165824);           // 8.4 MB
  u16*  Qs  = (u16*)(ws + 33554432);           // Qs/Kb/Vb contiguous (seg stride 8388608 elems)
  u16*  Kb  = (u16*)(ws + 50331648);
  u16*  Vb  = (u16*)(ws + 67108864);
  u16*  Z   = (u16*)(ws + 83886080);           // 33.6 MB
  float* R  = (float*)(ws + 117440512);        // 67.1 MB -> total 184.5 MB
  u16*  out1 = xb;

  // conversions
  k_cvt<0><<<ROWS * DM / 4 / 256, 256, 0, stream>>>(x, xb, ROWS * DM / 4);
  k_cvt<0><<<DM * DM / 4 / 256, 256, 0, stream>>>(Wq, Wqb, DM * DM / 4);
  k_cvt<0><<<DM * DM / 4 / 256, 256, 0, stream>>>(Wk, Wkb, DM * DM / 4);
  k_cvt<0><<<DM * DM / 4 / 256, 256, 0, stream>>>(Wv, Wvb, DM * DM / 4);
  k_cvt<0><<<DM * DM / 4 / 256, 256, 0, stream>>>(Wo, Wob, DM * DM / 4);
  k_cvt<1><<<SEQ * SEQ / 4 / 256, 256, 0, stream>>>(wbias, EW, SEQ * SEQ / 4);

  // fused QKV projection: A=xb [8192,1024], B=Wall [3072,1024] -> Qs|Kb|Vb
  dim3 gqkv(3072 / 256, ROWS / 256, 1);
  k_big<1024, 1><<<gqkv, 512, 0, stream>>>(xb, Wqb, Qs, bq, bk, bv, 0, 0);

  // transpose + exp into Z
  dim3 gt(SEQ / 64, DM / 64, NB);
  k_trans<<<gt, 256, 0, stream>>>(Kb, Vb, Z);

  // AFT core: R[b] = EW @ Z[b]^T  (256^2 8-phase, unchanged schedule)
  dim3 g8(8, 8, NB);
  k_big<2048, 0><<<g8, 512, 0, stream>>>(EW, Z, R, nullptr, nullptr, nullptr,
                                         (long)2 * DM * SEQ, (long)SEQ * 2 * DM);

  // combine
  k_combine<<<ROWS * DM / 4 / 256, 256, 0, stream>>>(Qs, R, out1);

  // output projection -> f32 d_out
  dim3 gop(DM / 256, ROWS / 256, 1);
  k_big<1024, 2><<<gop, 512, 0, stream>>>(out1, Wob, (float*)d_out, bo, nullptr,
                                          nullptr, 0, 0);
}

// Round 8
// 321.854 us; speedup vs baseline: 1.3537x; 1.0460x over previous
//
#include <hip/hip_runtime.h>
#include <stdint.h>

typedef unsigned short u16;
typedef __attribute__((ext_vector_type(8))) short short8;
typedef __attribute__((ext_vector_type(4))) float f32x4;

#define SEQ 2048
#define DM 1024
#define NB 4
#define ROWS (NB*SEQ)   // 8192

__device__ __forceinline__ u16 f2bf(float f) {
  union { float f; uint32_t u; } x; x.f = f;
  uint32_t u = x.u;
  uint32_t r = u + 0x7FFFu + ((u >> 16) & 1u);
  return (u16)(r >> 16);
}
__device__ __forceinline__ float bf2f(u16 h) {
  union { uint32_t u; float f; } x; x.u = ((uint32_t)h) << 16;
  return x.f;
}

__device__ __forceinline__ void g2l16(void* lds, const void* g) {
  __builtin_amdgcn_global_load_lds(
      (const __attribute__((address_space(1))) void*)g,
      (__attribute__((address_space(3))) void*)lds, 16, 0, 0);
}

// ---------------- convert: f32 -> bf16 (MODE 1 applies exp first) ----------
template<int MODE>
__global__ void k_cvt(const float* __restrict__ in, u16* __restrict__ out, int n4) {
  int i = blockIdx.x * 256 + threadIdx.x;
  if (i >= n4) return;
  float4 v = reinterpret_cast<const float4*>(in)[i];
  if (MODE == 1) { v.x = __expf(v.x); v.y = __expf(v.y); v.z = __expf(v.z); v.w = __expf(v.w); }
  ushort4 o;
  o.x = f2bf(v.x); o.y = f2bf(v.y); o.z = f2bf(v.z); o.w = f2bf(v.w);
  reinterpret_cast<ushort4*>(out)[i] = o;
}

// ---------------- 256xBN / BK=64 / 8-wave GEMM, 8-phase-style schedule ------
// C[m,n] = sum_k A[m,k] * B[n,k]; A:[M,KD] B:[N,KD] row-major bf16.
// WM = waves in M (2 -> BN=256 for AFT; 4 -> BN=128 for QKV/out-proj, fixing
// grid quantization: 768=3.0 and 256=1.0 rounds instead of 1.5/0.5).
// Schedule identical to R6-verified kernel: T2 swizzle both-sides, counted
// vmcnt (loads/stage in flight), setprio clusters, STAGE pinned below the
// bottom s_barrier by sched_barrier(0) (R6 race fix).
// MODE 0: f32 out, ldc=2048, batched via blockIdx.z (AFT core).
// MODE 1: fused QKV epilogue — N=3072, 3 segments {Q:sigmoid, K, V}, bf16.
// MODE 2: f32 out + bias b0, ldc=1024 (out-proj).
#define STAGE(t_, bf_) do { \
  _Pragma("unroll") for (int c = 0; c < 4; ++c) { \
    int idx = c * 512 + tid; \
    int r = idx >> 3; \
    int ce = ((idx & 7) ^ (r & 7)) * 8; \
    g2l16(&lds[(bf_)*BUFE + idx*8], Ag + (long)r*KD + (t_)*64 + ce); \
  } \
  _Pragma("unroll") for (int c = 0; c < BN/64; ++c) { \
    int idx = c * 512 + tid; \
    int r = idx >> 3; \
    int ce = ((idx & 7) ^ (r & 7)) * 8; \
    g2l16(&lds[(bf_)*BUFE + 16384 + idx*8], Bg + (long)r*KD + (t_)*64 + ce); \
  } } while (0)

#define LDA8(mh_) do { \
  _Pragma("unroll") for (int i = 0; i < FM/2; ++i) \
  _Pragma("unroll") for (int k = 0; k < 2; ++k) \
    a[i][k] = *(const short8*)&lds[ab + ((mh_)*(RW/2) + i*16 + lr)*64 + 8*(((k<<2)|kg) ^ (lr&7))]; \
  } while (0)

#define LDB8(nh_) do { \
  _Pragma("unroll") for (int j = 0; j < 2; ++j) \
  _Pragma("unroll") for (int k = 0; k < 2; ++k) \
    bn[nh_][j][k] = *(const short8*)&lds[bb + (((nh_)*2+j)*16 + lr)*64 + 8*(((k<<2)|kg) ^ (lr&7))]; \
  } while (0)

#define MM8(mh_, nh_) do { \
  asm volatile("s_waitcnt lgkmcnt(0)" ::: "memory"); \
  __builtin_amdgcn_sched_barrier(0); \
  __builtin_amdgcn_s_setprio(1); \
  _Pragma("unroll") for (int i = 0; i < FM/2; ++i) \
  _Pragma("unroll") for (int j = 0; j < 2; ++j) \
  _Pragma("unroll") for (int k = 0; k < 2; ++k) \
    acc[(mh_)*(FM/2)+i][(nh_)*2+j] = __builtin_amdgcn_mfma_f32_16x16x32_bf16( \
        a[i][k], bn[nh_][j][k], acc[(mh_)*(FM/2)+i][(nh_)*2+j], 0, 0, 0); \
  __builtin_amdgcn_s_setprio(0); \
  } while (0)

template<int KD, int WM, int MODE>
__global__ __launch_bounds__(512)
void k_big(const u16* __restrict__ A, const u16* __restrict__ B,
           void* __restrict__ Cv,
           const float* __restrict__ b0, const float* __restrict__ b1,
           const float* __restrict__ b2, long sB, long sC)
{
  constexpr int WN = 8 / WM;           // waves in N
  constexpr int BN = WN * 64;          // 256 or 128
  constexpr int RW = 256 / WM;         // rows per wave: 128 or 64
  constexpr int FM = RW / 16;          // m-frags per wave: 8 or 4
  constexpr int NT = KD / 64;
  constexpr int BUFE = (256 + BN) * 64;  // u16 elems per buffer
  __shared__ u16 lds[2 * BUFE];        // 128 KiB (BN=256) or 96 KiB (BN=128)
  const int tid = threadIdx.x;
  const int l  = tid & 63, wid = tid >> 6;
  const int wm = wid / WN, wn = wid % WN;
  const int lr = l & 15,  kg = l >> 4;
  const int brow = blockIdx.y * 256;
  const int bcol = blockIdx.x * BN;
  const u16* Ag = A + (long)brow * KD;
  const u16* Bg = B + (long)blockIdx.z * sB + (long)bcol * KD;

  f32x4 acc[FM][4];
#pragma unroll
  for (int m = 0; m < FM; ++m)
#pragma unroll
    for (int n = 0; n < 4; ++n) acc[m][n] = (f32x4){0.f, 0.f, 0.f, 0.f};

  short8 a[FM/2][2], bn[2][2][2];

  STAGE(0, 0);
  STAGE(1, 1);

  for (int t = 0; t < NT; ++t) {
    const int bf = t & 1;
    if (t == NT - 1)              asm volatile("s_waitcnt vmcnt(0)" ::: "memory");
    else if constexpr (BN == 256) asm volatile("s_waitcnt vmcnt(8)" ::: "memory");
    else                          asm volatile("s_waitcnt vmcnt(6)" ::: "memory");
    __builtin_amdgcn_s_barrier();
    __builtin_amdgcn_sched_barrier(0);
    const int ab = bf*BUFE + wm*RW*64;
    const int bb = bf*BUFE + 16384 + wn*64*64;
    LDA8(0); LDB8(0); MM8(0, 0);
    LDB8(1);          MM8(0, 1);
    LDA8(1);          MM8(1, 1);
                      MM8(1, 0);
    __builtin_amdgcn_sched_barrier(0);
    __builtin_amdgcn_s_barrier();
    __builtin_amdgcn_sched_barrier(0);   // R6 race fix: pin STAGE below barrier
    if (t + 2 < NT) STAGE(t + 2, bf);
  }

#pragma unroll
  for (int m = 0; m < FM; ++m)
#pragma unroll
    for (int n = 0; n < 4; ++n)
#pragma unroll
      for (int r = 0; r < 4; ++r) {
        int row = brow + wm*RW + m*16 + kg*4 + r;
        int col = bcol + wn*64 + n*16 + lr;
        float v = acc[m][n][r];
        if (MODE == 0) {
          ((float*)Cv)[(long)blockIdx.z * sC + (long)row * 2048 + col] = v;
        } else if (MODE == 1) {
          int seg = col >> 10, colr = col & 1023;
          const float* bp = (seg == 0) ? b0 : (seg == 1) ? b1 : b2;
          v += bp[colr];
          if (seg == 0) v = 1.f / (1.f + __expf(-v));
          ((u16*)Cv)[(long)seg * 8388608 + (long)row * 1024 + colr] = f2bf(v);
        } else {
          ((float*)Cv)[(long)row * 1024 + col] = v + b0[col];
        }
      }
}

// ---------------- transpose + exp: Kb,Vb [b*T+s, e] bf16 -> Z[b][{eKV,eK}][e][s] bf16
__global__ void k_trans(const u16* __restrict__ Kb, const u16* __restrict__ Vb,
                        u16* __restrict__ Z) {
  __shared__ u16 lk[64][65];
  __shared__ u16 lv[64][65];
  int s0 = blockIdx.x * 64, e0 = blockIdx.y * 64, b = blockIdx.z;
  int tx = threadIdx.x & 63, ty = threadIdx.x >> 6;
  const long baseIn = (long)b * SEQ * DM;
  for (int j = ty; j < 64; j += 4) {
    lk[j][tx] = Kb[baseIn + (long)(s0 + j) * DM + e0 + tx];
    lv[j][tx] = Vb[baseIn + (long)(s0 + j) * DM + e0 + tx];
  }
  __syncthreads();
  const long ob = (long)b * 2 * DM * SEQ;
  for (int j = ty; j < 64; j += 4) {
    int e = e0 + j;
    float kf = bf2f(lk[tx][j]);
    float vf = bf2f(lv[tx][j]);
    float ek = __expf(kf);
    Z[ob + (long)e * SEQ + s0 + tx]        = f2bf(ek * vf);
    Z[ob + (long)(DM + e) * SEQ + s0 + tx] = f2bf(ek);
  }
}

// ---------------- combine: out1 = sigQ * numer/denom  -> bf16
__global__ void k_combine(const u16* __restrict__ Qs, const float* __restrict__ R,
                          u16* __restrict__ out1) {
  long i4 = (long)blockIdx.x * 256 + threadIdx.x;
  if (i4 >= (long)ROWS * DM / 4) return;
  long i = i4 * 4;
  int e = (int)(i & (DM - 1));
  long row = i >> 10;
  float4 nu = *(const float4*)&R[row * (2 * DM) + e];
  float4 de = *(const float4*)&R[row * (2 * DM) + DM + e];
  ushort4 q = *(const ushort4*)&Qs[i];
  ushort4 o;
  o.x = f2bf(bf2f(q.x) * nu.x / de.x);
  o.y = f2bf(bf2f(q.y) * nu.y / de.y);
  o.z = f2bf(bf2f(q.z) * nu.z / de.z);
  o.w = f2bf(bf2f(q.w) * nu.w / de.w);
  *(ushort4*)&out1[i] = o;
}

extern "C" void kernel_launch(void* const* d_in, const int* in_sizes, int n_in,
                              void* d_out, int out_size, void* d_ws, size_t ws_size,
                              hipStream_t stream)
{
  const float* x     = (const float*)d_in[0];
  const float* Wq    = (const float*)d_in[2];
  const float* bq    = (const float*)d_in[3];
  const float* Wk    = (const float*)d_in[4];
  const float* bk    = (const float*)d_in[5];
  const float* Wv    = (const float*)d_in[6];
  const float* bv    = (const float*)d_in[7];
  const float* Wo    = (const float*)d_in[8];
  const float* bo    = (const float*)d_in[9];
  const float* wbias = (const float*)d_in[10];

  char* ws = (char*)d_ws;
  u16*  xb  = (u16*)(ws);                      // 16.8 MB (reused as out1)
  u16*  Wqb = (u16*)(ws + 16777216);           // Wq/Wk/Wv contiguous = Wall[3072][1024]
  u16*  Wkb = Wqb + 1024 * 1024;
  u16*  Wvb = Wkb + 1024 * 1024;
  u16*  Wob = Wvb + 1024 * 1024;
  u16*  EW  = (u16*)(ws + 25165824);           // 8.4 MB
  u16*  Qs  = (u16*)(ws + 33554432);           // Qs/Kb/Vb contiguous (seg stride 8388608 elems)
  u16*  Kb  = (u16*)(ws + 50331648);
  u16*  Vb  = (u16*)(ws + 67108864);
  u16*  Z   = (u16*)(ws + 83886080);           // 33.6 MB
  float* R  = (float*)(ws + 117440512);        // 67.1 MB -> total 184.5 MB
  u16*  out1 = xb;

  // conversions
  k_cvt<0><<<ROWS * DM / 4 / 256, 256, 0, stream>>>(x, xb, ROWS * DM / 4);
  k_cvt<0><<<DM * DM / 4 / 256, 256, 0, stream>>>(Wq, Wqb, DM * DM / 4);
  k_cvt<0><<<DM * DM / 4 / 256, 256, 0, stream>>>(Wk, Wkb, DM * DM / 4);
  k_cvt<0><<<DM * DM / 4 / 256, 256, 0, stream>>>(Wv, Wvb, DM * DM / 4);
  k_cvt<0><<<DM * DM / 4 / 256, 256, 0, stream>>>(Wo, Wob, DM * DM / 4);
  k_cvt<1><<<SEQ * SEQ / 4 / 256, 256, 0, stream>>>(wbias, EW, SEQ * SEQ / 4);

  // fused QKV projection: A=xb [8192,1024], B=Wall [3072,1024] -> Qs|Kb|Vb
  // BN=128 -> grid 24x32 = 768 blocks = 3.0 rounds/CU (was 384 = 1.5)
  dim3 gqkv(3072 / 128, ROWS / 256, 1);
  k_big<1024, 4, 1><<<gqkv, 512, 0, stream>>>(xb, Wqb, Qs, bq, bk, bv, 0, 0);

  // transpose + exp into Z
  dim3 gt(SEQ / 64, DM / 64, NB);
  k_trans<<<gt, 256, 0, stream>>>(Kb, Vb, Z);

  // AFT core: R[b] = EW @ Z[b]^T  (256^2, unchanged WM=2 instantiation)
  dim3 g8(8, 8, NB);
  k_big<2048, 2, 0><<<g8, 512, 0, stream>>>(EW, Z, R, nullptr, nullptr, nullptr,
                                            (long)2 * DM * SEQ, (long)SEQ * 2 * DM);

  // combine
  k_combine<<<ROWS * DM / 4 / 256, 256, 0, stream>>>(Qs, R, out1);

  // output projection -> f32 d_out  (BN=128 -> 8x32 = 256 blocks = 1.0 round)
  dim3 gop(DM / 128, ROWS / 256, 1);
  k_big<1024, 4, 2><<<gop, 512, 0, stream>>>(out1, Wob, (float*)d_out, bo, nullptr,
                                             nullptr, 0, 0);
}

// Round 9
// 288.254 us; speedup vs baseline: 1.5115x; 1.1166x over previous
//
#include <hip/hip_runtime.h>
#include <stdint.h>

typedef unsigned short u16;
typedef __attribute__((ext_vector_type(8))) short short8;
typedef __attribute__((ext_vector_type(4))) float f32x4;

#define SEQ 2048
#define DM 1024
#define NB 4
#define ROWS (NB*SEQ)   // 8192

__device__ __forceinline__ u16 f2bf(float f) {
  union { float f; uint32_t u; } x; x.f = f;
  uint32_t u = x.u;
  uint32_t r = u + 0x7FFFu + ((u >> 16) & 1u);
  return (u16)(r >> 16);
}
__device__ __forceinline__ float bf2f(u16 h) {
  union { uint32_t u; float f; } x; x.u = ((uint32_t)h) << 16;
  return x.f;
}

__device__ __forceinline__ void g2l16(void* lds, const void* g) {
  __builtin_amdgcn_global_load_lds(
      (const __attribute__((address_space(1))) void*)g,
      (__attribute__((address_space(3))) void*)lds, 16, 0, 0);
}

// ---------------- fused convert: one kernel for all f32->bf16 staging ------
// f4-index ranges: [0,2097152) x -> xb; then 4x262144 W -> Wqb..Wob;
// [3145728,4194304) wbias -> exp -> EW.
__global__ void k_cvt_all(const float* __restrict__ x,
                          const float* __restrict__ Wq, const float* __restrict__ Wk,
                          const float* __restrict__ Wv, const float* __restrict__ Wo,
                          const float* __restrict__ wb, u16* __restrict__ dws) {
  int i = blockIdx.x * 256 + threadIdx.x;   // f4 index, 4194304 total
  const float* src; long dst; bool ex = false;
  if (i < 2097152) { src = x + (long)i * 4; dst = (long)i * 4; }
  else if (i < 3145728) {
    int j = i - 2097152, which = j >> 18, o = j & 262143;
    const float* Wp = (which == 0) ? Wq : (which == 1) ? Wk : (which == 2) ? Wv : Wo;
    src = Wp + (long)o * 4; dst = 8388608 + (long)(j) * 4;
  } else { int j = i - 3145728; src = wb + (long)j * 4; dst = 12582912 + (long)j * 4; ex = true; }
  float4 v = *(const float4*)src;
  if (ex) { v.x = __expf(v.x); v.y = __expf(v.y); v.z = __expf(v.z); v.w = __expf(v.w); }
  ushort4 o4; o4.x = f2bf(v.x); o4.y = f2bf(v.y); o4.z = f2bf(v.z); o4.w = f2bf(v.w);
  *(ushort4*)(dws + dst) = o4;
}

// ---------------- 256xBN / BK=64 / 8-wave GEMM, 8-phase-style schedule ------
// C[m,n] = sum_k A[m,k] * B[n,k]; A:[M,KD] B:[N,KD] row-major bf16.
// Schedule identical to R6-verified kernel: T2 swizzle both-sides, counted
// vmcnt, setprio clusters, STAGE pinned below bottom barrier (R6 race fix).
// MODE 1: fused QKV epilogue (WM=4, BN=128, 3 segments {Q:sigmoid,K,V}, bf16)
// MODE 2: f32 out + bias b0, ldc=1024 (out-proj, WM=4)
// MODE 3: AFT-ratio (WM=2): B-tile = 128 eKV rows + 128 eK rows for the SAME
//   e-columns; frags n=0,1 = numer, n=2,3 = denom at e = bcol+wn*32+j*16+lr
//   (lane-local ratio). Epilogue: out1 = sigQ * numer * rcp(denom) -> bf16.
//   Eliminates the f32 R buffer (134 MB round-trip) and the combine kernel.
#define STAGE(t_, bf_) do { \
  _Pragma("unroll") for (int c = 0; c < 4; ++c) { \
    int idx = c * 512 + tid; \
    int r = idx >> 3; \
    int ce = ((idx & 7) ^ (r & 7)) * 8; \
    g2l16(&lds[(bf_)*BUFE + idx*8], Ag + (long)r*KD + (t_)*64 + ce); \
  } \
  _Pragma("unroll") for (int c = 0; c < BN/64; ++c) { \
    int idx = c * 512 + tid; \
    int r = idx >> 3; \
    int ce = ((idx & 7) ^ (r & 7)) * 8; \
    const u16* bp_ = (MODE == 3 && c >= 2) ? (Bg + 896L*KD) : Bg; \
    g2l16(&lds[(bf_)*BUFE + 16384 + idx*8], bp_ + (long)r*KD + (t_)*64 + ce); \
  } } while (0)

#define LDA8(mh_) do { \
  _Pragma("unroll") for (int i = 0; i < FM/2; ++i) \
  _Pragma("unroll") for (int k = 0; k < 2; ++k) \
    a[i][k] = *(const short8*)&lds[ab + ((mh_)*(RW/2) + i*16 + lr)*64 + 8*(((k<<2)|kg) ^ (lr&7))]; \
  } while (0)

#define LDB8(nh_) do { \
  _Pragma("unroll") for (int j = 0; j < 2; ++j) \
  _Pragma("unroll") for (int k = 0; k < 2; ++k) { \
    int rowB_ = (MODE == 3) ? ((nh_)*128 + wn*32 + j*16 + lr) \
                            : (wn*64 + ((nh_)*2+j)*16 + lr); \
    bn[nh_][j][k] = *(const short8*)&lds[bb + rowB_*64 + 8*(((k<<2)|kg) ^ (lr&7))]; \
  } } while (0)

#define MM8(mh_, nh_) do { \
  asm volatile("s_waitcnt lgkmcnt(0)" ::: "memory"); \
  __builtin_amdgcn_sched_barrier(0); \
  __builtin_amdgcn_s_setprio(1); \
  _Pragma("unroll") for (int i = 0; i < FM/2; ++i) \
  _Pragma("unroll") for (int j = 0; j < 2; ++j) \
  _Pragma("unroll") for (int k = 0; k < 2; ++k) \
    acc[(mh_)*(FM/2)+i][(nh_)*2+j] = __builtin_amdgcn_mfma_f32_16x16x32_bf16( \
        a[i][k], bn[nh_][j][k], acc[(mh_)*(FM/2)+i][(nh_)*2+j], 0, 0, 0); \
  __builtin_amdgcn_s_setprio(0); \
  } while (0)

template<int KD, int WM, int MODE>
__global__ __launch_bounds__(512)
void k_big(const u16* __restrict__ A, const u16* __restrict__ B,
           void* __restrict__ Cv,
           const float* __restrict__ b0, const float* __restrict__ b1,
           const float* __restrict__ b2, long sB, long sC)
{
  constexpr int WN = 8 / WM;           // waves in N
  constexpr int BN = WN * 64;          // 256 or 128
  constexpr int RW = 256 / WM;         // rows per wave: 128 or 64
  constexpr int FM = RW / 16;          // m-frags per wave: 8 or 4
  constexpr int NT = KD / 64;
  constexpr int BUFE = (256 + BN) * 64;  // u16 elems per buffer
  __shared__ u16 lds[2 * BUFE];        // 128 KiB (BN=256) or 96 KiB (BN=128)
  const int tid = threadIdx.x;
  const int l  = tid & 63, wid = tid >> 6;
  const int wm = wid / WN, wn = wid % WN;
  const int lr = l & 15,  kg = l >> 4;
  const int brow = blockIdx.y * 256;
  const int bcol = blockIdx.x * ((MODE == 3) ? 128 : BN);
  const u16* Ag = A + (long)brow * KD;
  const u16* Bg = B + (long)blockIdx.z * sB + (long)bcol * KD;

  f32x4 acc[FM][4];
#pragma unroll
  for (int m = 0; m < FM; ++m)
#pragma unroll
    for (int n = 0; n < 4; ++n) acc[m][n] = (f32x4){0.f, 0.f, 0.f, 0.f};

  short8 a[FM/2][2], bn[2][2][2];

  STAGE(0, 0);
  STAGE(1, 1);

  for (int t = 0; t < NT; ++t) {
    const int bf = t & 1;
    if (t == NT - 1)              asm volatile("s_waitcnt vmcnt(0)" ::: "memory");
    else if constexpr (BN == 256) asm volatile("s_waitcnt vmcnt(8)" ::: "memory");
    else                          asm volatile("s_waitcnt vmcnt(6)" ::: "memory");
    __builtin_amdgcn_s_barrier();
    __builtin_amdgcn_sched_barrier(0);
    const int ab = bf*BUFE + wm*RW*64;
    const int bb = bf*BUFE + 16384;
    LDA8(0); LDB8(0); MM8(0, 0);
    LDB8(1);          MM8(0, 1);
    LDA8(1);          MM8(1, 1);
                      MM8(1, 0);
    __builtin_amdgcn_sched_barrier(0);
    __builtin_amdgcn_s_barrier();
    __builtin_amdgcn_sched_barrier(0);   // R6 race fix: pin STAGE below barrier
    if (t + 2 < NT) STAGE(t + 2, bf);
  }

  if constexpr (MODE == 3) {
    const u16* QsP = (const u16*)b0;
    u16* O = (u16*)Cv;
    const long rb = (long)blockIdx.z * 2048;
#pragma unroll
    for (int m = 0; m < FM; ++m)
#pragma unroll
      for (int j = 0; j < 2; ++j)
#pragma unroll
        for (int r = 0; r < 4; ++r) {
          int row = brow + wm*RW + m*16 + kg*4 + r;
          int e = bcol + wn*32 + j*16 + lr;
          float nu = acc[m][j][r];
          float de = acc[m][2+j][r];
          float q = bf2f(QsP[(rb + row) * 1024 + e]);
          O[(rb + row) * 1024 + e] = f2bf(q * nu * __builtin_amdgcn_rcpf(de));
        }
  } else {
#pragma unroll
    for (int m = 0; m < FM; ++m)
#pragma unroll
      for (int n = 0; n < 4; ++n)
#pragma unroll
        for (int r = 0; r < 4; ++r) {
          int row = brow + wm*RW + m*16 + kg*4 + r;
          int col = bcol + wn*64 + n*16 + lr;
          float v = acc[m][n][r];
          if (MODE == 1) {
            int seg = col >> 10, colr = col & 1023;
            const float* bp = (seg == 0) ? b0 : (seg == 1) ? b1 : b2;
            v += bp[colr];
            if (seg == 0) v = 1.f / (1.f + __expf(-v));
            ((u16*)Cv)[(long)seg * 8388608 + (long)row * 1024 + colr] = f2bf(v);
          } else {
            ((float*)Cv)[(long)row * 1024 + col] = v + b0[col];
          }
        }
  }
}

// ---------------- transpose + exp: Kb,Vb [b*T+s, e] bf16 -> Z[b][{eKV,eK}][e][s] bf16
__global__ void k_trans(const u16* __restrict__ Kb, const u16* __restrict__ Vb,
                        u16* __restrict__ Z) {
  __shared__ u16 lk[64][65];
  __shared__ u16 lv[64][65];
  int s0 = blockIdx.x * 64, e0 = blockIdx.y * 64, b = blockIdx.z;
  int tx = threadIdx.x & 63, ty = threadIdx.x >> 6;
  const long baseIn = (long)b * SEQ * DM;
  for (int j = ty; j < 64; j += 4) {
    lk[j][tx] = Kb[baseIn + (long)(s0 + j) * DM + e0 + tx];
    lv[j][tx] = Vb[baseIn + (long)(s0 + j) * DM + e0 + tx];
  }
  __syncthreads();
  const long ob = (long)b * 2 * DM * SEQ;
  for (int j = ty; j < 64; j += 4) {
    int e = e0 + j;
    float kf = bf2f(lk[tx][j]);
    float vf = bf2f(lv[tx][j]);
    float ek = __expf(kf);
    Z[ob + (long)e * SEQ + s0 + tx]        = f2bf(ek * vf);
    Z[ob + (long)(DM + e) * SEQ + s0 + tx] = f2bf(ek);
  }
}

extern "C" void kernel_launch(void* const* d_in, const int* in_sizes, int n_in,
                              void* d_out, int out_size, void* d_ws, size_t ws_size,
                              hipStream_t stream)
{
  const float* x     = (const float*)d_in[0];
  const float* Wq    = (const float*)d_in[2];
  const float* bq    = (const float*)d_in[3];
  const float* Wk    = (const float*)d_in[4];
  const float* bk    = (const float*)d_in[5];
  const float* Wv    = (const float*)d_in[6];
  const float* bv    = (const float*)d_in[7];
  const float* Wo    = (const float*)d_in[8];
  const float* bo    = (const float*)d_in[9];
  const float* wbias = (const float*)d_in[10];

  char* ws = (char*)d_ws;
  u16*  xb  = (u16*)(ws);                      // 16.8 MB (reused as out1)
  u16*  Wqb = (u16*)(ws + 16777216);           // Wq/Wk/Wv contiguous = Wall[3072][1024]
  u16*  Wob = (u16*)(ws + 16777216 + 3 * 2097152);
  u16*  EW  = (u16*)(ws + 25165824);           // 8.4 MB
  u16*  Qs  = (u16*)(ws + 33554432);           // Qs/Kb/Vb contiguous (seg stride 8388608)
  u16*  Kb  = (u16*)(ws + 50331648);
  u16*  Vb  = (u16*)(ws + 67108864);
  u16*  Z   = (u16*)(ws + 83886080);           // 33.6 MB -> total 117.4 MB
  u16*  out1 = xb;

  // all f32->bf16 conversions in one kernel (was 6 launches)
  k_cvt_all<<<16384, 256, 0, stream>>>(x, Wq, Wk, Wv, Wo, wbias, (u16*)ws);

  // fused QKV projection: A=xb [8192,1024], B=Wall [3072,1024] -> Qs|Kb|Vb
  dim3 gqkv(3072 / 128, ROWS / 256, 1);
  k_big<1024, 4, 1><<<gqkv, 512, 0, stream>>>(xb, Wqb, Qs, bq, bk, bv, 0, 0);

  // transpose + exp into Z
  dim3 gt(SEQ / 64, DM / 64, NB);
  k_trans<<<gt, 256, 0, stream>>>(Kb, Vb, Z);

  // AFT core + ratio + sigmoid-Q combine, fused: out1 = sigQ * numer/denom
  dim3 g8(8, 8, NB);
  k_big<2048, 2, 3><<<g8, 512, 0, stream>>>(EW, Z, out1, (const float*)Qs,
                                            nullptr, nullptr,
                                            (long)2 * DM * SEQ, 0);

  // output projection -> f32 d_out  (BN=128 -> 8x32 = 256 blocks = 1.0 round)
  dim3 gop(DM / 128, ROWS / 256, 1);
  k_big<1024, 4, 2><<<gop, 512, 0, stream>>>(out1, Wob, (float*)d_out, bo, nullptr,
                                             nullptr, 0, 0);
}